// Round 5
// baseline (709.228 us; speedup 1.0000x reference)
//
#include <hip/hip_runtime.h>
#include <cstdint>
#include <cstddef>

typedef __attribute__((ext_vector_type(8))) short short8;
typedef __attribute__((ext_vector_type(4))) float floatx4;

#define DEV static __device__ __forceinline__

DEV unsigned short f2bf(float f) {
  union { float f; uint32_t u; } v; v.f = f;
  uint32_t r = v.u + 0x7fffu + ((v.u >> 16) & 1u);
  return (unsigned short)(r >> 16);
}
DEV float bf2f(unsigned short h) {
  union { uint32_t u; float f; } v; v.u = ((uint32_t)h) << 16; return v.f;
}
DEV float sigmoidf_(float x) { return 1.f / (1.f + __expf(-x)); }

DEV void gld_lds16(const unsigned short* g, unsigned short* l) {
  __builtin_amdgcn_global_load_lds(
      (const __attribute__((address_space(1))) void*)g,
      (__attribute__((address_space(3))) void*)l, 16, 0, 0);
}

// ---------------------------------------------------------------------------
// fp32 (Kdim x Ndim) row-major -> bf16 (Ndim x Kdim) row-major
// ---------------------------------------------------------------------------
__global__ __launch_bounds__(256) void transpose_kernel(
    const float* __restrict__ W, unsigned short* __restrict__ Wt,
    int Kdim, int Ndim) {
  __shared__ float tile[32][33];
  const int n0 = blockIdx.x * 32;
  const int k0 = blockIdx.y * 32;
  const int tx = threadIdx.x & 31;
  const int ty = threadIdx.x >> 5;
#pragma unroll
  for (int r = 0; r < 32; r += 8)
    tile[ty + r][tx] = W[(size_t)(k0 + ty + r) * Ndim + n0 + tx];
  __syncthreads();
#pragma unroll
  for (int r = 0; r < 32; r += 8)
    Wt[(size_t)(n0 + ty + r) * Kdim + k0 + tx] = f2bf(tile[tx][ty + r]);
}

// flat fp32 -> bf16 cast, 4 elements/thread
__global__ __launch_bounds__(256) void cast_kernel(
    const float* __restrict__ W, unsigned short* __restrict__ Wb) {
  const size_t i = (size_t)blockIdx.x * 256 + threadIdx.x;
  const float4 v = ((const float4*)W)[i];
  ushort4 o;
  o.x = f2bf(v.x); o.y = f2bf(v.y); o.z = f2bf(v.z); o.w = f2bf(v.w);
  ((ushort4*)Wb)[i] = o;
}

// ---------------------------------------------------------------------------
// RMSNorm + u (bf16) + gl logit per row. One block per row.
// ---------------------------------------------------------------------------
__global__ __launch_bounds__(256) void rmsnorm_kernel(
    const float* __restrict__ x, const float* __restrict__ gl_w,
    const float* __restrict__ gl_b, unsigned short* __restrict__ u,
    float* __restrict__ gl_logit) {
  const int row = blockIdx.x;
  const int tid = threadIdx.x;
  const float4 v = ((const float4*)(x + (size_t)row * 1024))[tid];
  float ss = v.x * v.x + v.y * v.y + v.z * v.z + v.w * v.w;
#pragma unroll
  for (int o = 32; o > 0; o >>= 1) ss += __shfl_down(ss, o, 64);
  __shared__ float red[4];
  if ((tid & 63) == 0) red[tid >> 6] = ss;
  __syncthreads();
  const float tot = red[0] + red[1] + red[2] + red[3];
  const float r = rsqrtf(tot * (1.f / 1024.f) + 1e-6f);
  const float ux = v.x * r, uy = v.y * r, uz = v.z * r, uw = v.w * r;
  ushort4 ub;
  ub.x = f2bf(ux); ub.y = f2bf(uy); ub.z = f2bf(uz); ub.w = f2bf(uw);
  ((ushort4*)(u + (size_t)row * 1024))[tid] = ub;
  const float4 w4 = ((const float4*)gl_w)[tid];
  float dot = ux * w4.x + uy * w4.y + uz * w4.z + uw * w4.w;
#pragma unroll
  for (int o = 32; o > 0; o >>= 1) dot += __shfl_down(dot, o, 64);
  __syncthreads();
  if ((tid & 63) == 0) red[tid >> 6] = dot;
  __syncthreads();
  if (tid == 0) gl_logit[row] = red[0] + red[1] + red[2] + red[3] + gl_b[0];
}

// ---------------------------------------------------------------------------
// GEMM (direct): C = A * Bt^T, m97 structure. EPI 2 = bias+silu -> bf16.
// ---------------------------------------------------------------------------
template <int EPI>
__global__ __launch_bounds__(256, 2) void gemm_bt(
    const unsigned short* __restrict__ A, const unsigned short* __restrict__ Bt,
    const float* __restrict__ bias, void* __restrict__ Cout, int Ndim, int Kdim) {
  __shared__ unsigned short As[128 * 32];
  __shared__ unsigned short Bs[128 * 32];
  const int tid = threadIdx.x;
  const int wave = tid >> 6;
  const int lane = tid & 63;
  const size_t row0 = (size_t)blockIdx.x * 128;
  const size_t col0 = (size_t)blockIdx.y * 128;

  const int srow = wave * 32 + (lane >> 2);
  const int kofs = (lane & 3) * 8;
  const unsigned short* pA0 = A + (row0 + srow) * (size_t)Kdim + kofs;
  const unsigned short* pA1 = A + (row0 + srow + 16) * (size_t)Kdim + kofs;
  const unsigned short* pB0 = Bt + (col0 + srow) * (size_t)Kdim + kofs;
  const unsigned short* pB1 = Bt + (col0 + srow + 16) * (size_t)Kdim + kofs;
  unsigned short* lA0 = &As[(wave * 2 + 0) * 512];
  unsigned short* lA1 = &As[(wave * 2 + 1) * 512];
  unsigned short* lB0 = &Bs[(wave * 2 + 0) * 512];
  unsigned short* lB1 = &Bs[(wave * 2 + 1) * 512];

  const int wm = (wave & 1) * 64;
  const int wn = (wave >> 1) * 64;
  const int lr = lane & 15;
  const int lq = lane >> 4;
  const int a_off = (wm + lr) * 32 + lq * 8;
  const int b_off = (wn + lr) * 32 + lq * 8;

  floatx4 acc[4][4];
#pragma unroll
  for (int i = 0; i < 4; i++)
#pragma unroll
    for (int j = 0; j < 4; j++) acc[i][j] = floatx4{0.f, 0.f, 0.f, 0.f};

  for (int kt = 0; kt < Kdim; kt += 32) {
    __syncthreads();
    gld_lds16(pA0, lA0);
    gld_lds16(pA1, lA1);
    gld_lds16(pB0, lB0);
    gld_lds16(pB1, lB1);
    pA0 += 32; pA1 += 32; pB0 += 32; pB1 += 32;
    __syncthreads();
    short8 af[4], bfr[4];
#pragma unroll
    for (int i = 0; i < 4; i++) af[i] = *(const short8*)&As[a_off + i * 16 * 32];
#pragma unroll
    for (int j = 0; j < 4; j++) bfr[j] = *(const short8*)&Bs[b_off + j * 16 * 32];
#pragma unroll
    for (int i = 0; i < 4; i++)
#pragma unroll
      for (int j = 0; j < 4; j++)
        acc[i][j] = __builtin_amdgcn_mfma_f32_16x16x32_bf16(af[i], bfr[j], acc[i][j], 0, 0, 0);
  }

#pragma unroll
  for (int i = 0; i < 4; i++) {
    const size_t rbase = row0 + wm + 16 * i + lq * 4;
#pragma unroll
    for (int j = 0; j < 4; j++) {
      const size_t c = col0 + wn + 16 * j + lr;
#pragma unroll
      for (int r = 0; r < 4; r++) {
        float v = acc[i][j][r];
        const size_t off = (rbase + r) * (size_t)Ndim + c;
        if constexpr (EPI == 2) {
          v += bias[c];
          ((unsigned short*)Cout)[off] = f2bf(v * sigmoidf_(v));
        } else {
          ((unsigned short*)Cout)[off] = f2bf(v);
        }
      }
    }
  }
}

// ---------------------------------------------------------------------------
// Split-K GEMM with f32 atomic epilogue. blockIdx.z = split index.
// EPI 0: atomicAdd(Cacc+off, v)
// EPI 1: atomicAdd(Cacc+off, sigmoid(gl[row]) * v)
// ---------------------------------------------------------------------------
template <int EPI>
__global__ __launch_bounds__(256, 2) void gemm_atomic(
    const unsigned short* __restrict__ A, const unsigned short* __restrict__ Bt,
    float* __restrict__ Cacc, int Ndim, int Kdim, int splitLen,
    const float* __restrict__ gl) {
  __shared__ unsigned short As[128 * 32];
  __shared__ unsigned short Bs[128 * 32];
  const int k0 = blockIdx.z * splitLen;
  const int klen = min(splitLen, Kdim - k0);
  const int tid = threadIdx.x;
  const int wave = tid >> 6;
  const int lane = tid & 63;
  const size_t row0 = (size_t)blockIdx.x * 128;
  const size_t col0 = (size_t)blockIdx.y * 128;

  const int srow = wave * 32 + (lane >> 2);
  const int kofs = (lane & 3) * 8;
  const unsigned short* pA0 = A + (row0 + srow) * (size_t)Kdim + k0 + kofs;
  const unsigned short* pA1 = A + (row0 + srow + 16) * (size_t)Kdim + k0 + kofs;
  const unsigned short* pB0 = Bt + (col0 + srow) * (size_t)Kdim + k0 + kofs;
  const unsigned short* pB1 = Bt + (col0 + srow + 16) * (size_t)Kdim + k0 + kofs;
  unsigned short* lA0 = &As[(wave * 2 + 0) * 512];
  unsigned short* lA1 = &As[(wave * 2 + 1) * 512];
  unsigned short* lB0 = &Bs[(wave * 2 + 0) * 512];
  unsigned short* lB1 = &Bs[(wave * 2 + 1) * 512];

  const int wm = (wave & 1) * 64;
  const int wn = (wave >> 1) * 64;
  const int lr = lane & 15;
  const int lq = lane >> 4;
  const int a_off = (wm + lr) * 32 + lq * 8;
  const int b_off = (wn + lr) * 32 + lq * 8;

  floatx4 acc[4][4];
#pragma unroll
  for (int i = 0; i < 4; i++)
#pragma unroll
    for (int j = 0; j < 4; j++) acc[i][j] = floatx4{0.f, 0.f, 0.f, 0.f};

  for (int kt = 0; kt < klen; kt += 32) {
    __syncthreads();
    gld_lds16(pA0, lA0);
    gld_lds16(pA1, lA1);
    gld_lds16(pB0, lB0);
    gld_lds16(pB1, lB1);
    pA0 += 32; pA1 += 32; pB0 += 32; pB1 += 32;
    __syncthreads();
    short8 af[4], bfr[4];
#pragma unroll
    for (int i = 0; i < 4; i++) af[i] = *(const short8*)&As[a_off + i * 16 * 32];
#pragma unroll
    for (int j = 0; j < 4; j++) bfr[j] = *(const short8*)&Bs[b_off + j * 16 * 32];
#pragma unroll
    for (int i = 0; i < 4; i++)
#pragma unroll
      for (int j = 0; j < 4; j++)
        acc[i][j] = __builtin_amdgcn_mfma_f32_16x16x32_bf16(af[i], bfr[j], acc[i][j], 0, 0, 0);
  }

#pragma unroll
  for (int i = 0; i < 4; i++) {
    const size_t rbase = row0 + wm + 16 * i + lq * 4;
#pragma unroll
    for (int j = 0; j < 4; j++) {
      const size_t c = col0 + wn + 16 * j + lr;
#pragma unroll
      for (int r = 0; r < 4; r++) {
        const size_t row = rbase + r;
        const size_t off = row * (size_t)Ndim + c;
        if constexpr (EPI == 0) {
          atomicAdd(&Cacc[off], acc[i][j][r]);
        } else {
          const float g = sigmoidf_(gl[row]);
          atomicAdd(&Cacc[off], g * acc[i][j][r]);
        }
      }
    }
  }
}

// ---------------------------------------------------------------------------
// Batched strided GEMM for composite weights:
//   MT[d_out][kb*1024+d_in] = sum_dmid OT[d_out][kb*1024+dmid]*SB[d_in][kb*1024+dmid]
// ---------------------------------------------------------------------------
__global__ __launch_bounds__(256, 2) void gemm_mt(
    const unsigned short* __restrict__ OT, const unsigned short* __restrict__ SB,
    unsigned short* __restrict__ MT) {
  __shared__ unsigned short As[128 * 32];
  __shared__ unsigned short Bs[128 * 32];
  const int kb = blockIdx.z;
  const int tid = threadIdx.x;
  const int wave = tid >> 6;
  const int lane = tid & 63;
  const size_t row0 = (size_t)blockIdx.x * 128;
  const size_t col0 = (size_t)blockIdx.y * 128;
  const size_t ld = 16384;

  const int srow = wave * 32 + (lane >> 2);
  const int kofs = (lane & 3) * 8;
  const unsigned short* pA0 = OT + (row0 + srow) * ld + kb * 1024 + kofs;
  const unsigned short* pA1 = OT + (row0 + srow + 16) * ld + kb * 1024 + kofs;
  const unsigned short* pB0 = SB + (col0 + srow) * ld + kb * 1024 + kofs;
  const unsigned short* pB1 = SB + (col0 + srow + 16) * ld + kb * 1024 + kofs;
  unsigned short* lA0 = &As[(wave * 2 + 0) * 512];
  unsigned short* lA1 = &As[(wave * 2 + 1) * 512];
  unsigned short* lB0 = &Bs[(wave * 2 + 0) * 512];
  unsigned short* lB1 = &Bs[(wave * 2 + 1) * 512];

  const int wm = (wave & 1) * 64;
  const int wn = (wave >> 1) * 64;
  const int lr = lane & 15;
  const int lq = lane >> 4;
  const int a_off = (wm + lr) * 32 + lq * 8;
  const int b_off = (wn + lr) * 32 + lq * 8;

  floatx4 acc[4][4];
#pragma unroll
  for (int i = 0; i < 4; i++)
#pragma unroll
    for (int j = 0; j < 4; j++) acc[i][j] = floatx4{0.f, 0.f, 0.f, 0.f};

  for (int kt = 0; kt < 1024; kt += 32) {
    __syncthreads();
    gld_lds16(pA0, lA0);
    gld_lds16(pA1, lA1);
    gld_lds16(pB0, lB0);
    gld_lds16(pB1, lB1);
    pA0 += 32; pA1 += 32; pB0 += 32; pB1 += 32;
    __syncthreads();
    short8 af[4], bfr[4];
#pragma unroll
    for (int i = 0; i < 4; i++) af[i] = *(const short8*)&As[a_off + i * 16 * 32];
#pragma unroll
    for (int j = 0; j < 4; j++) bfr[j] = *(const short8*)&Bs[b_off + j * 16 * 32];
#pragma unroll
    for (int i = 0; i < 4; i++)
#pragma unroll
      for (int j = 0; j < 4; j++)
        acc[i][j] = __builtin_amdgcn_mfma_f32_16x16x32_bf16(af[i], bfr[j], acc[i][j], 0, 0, 0);
  }

#pragma unroll
  for (int i = 0; i < 4; i++) {
    const size_t rbase = row0 + wm + 16 * i + lq * 4;
#pragma unroll
    for (int j = 0; j < 4; j++) {
      const size_t c = col0 + wn + 16 * j + lr;
#pragma unroll
      for (int r = 0; r < 4; r++)
        MT[(rbase + r) * ld + kb * 1024 + c] = f2bf(acc[i][j][r]);
    }
  }
}

// ---------------------------------------------------------------------------
// h = conv7(u) * sigmoid(gacc + gate_b)   (gacc = u @ gate_w, f32 accumulated)
// ---------------------------------------------------------------------------
__global__ __launch_bounds__(256) void sigconv_kernel(
    const unsigned short* __restrict__ u, const float* __restrict__ conv_w,
    const float* __restrict__ gacc, const float* __restrict__ gate_b,
    unsigned short* __restrict__ h) {
  const size_t idx = (size_t)blockIdx.x * 256 + threadIdx.x;
  const int d = (int)(idx & 1023);
  const int t = (int)((idx >> 10) & 2047);
  const unsigned short* up = u + idx;
  float acc = 0.f;
#pragma unroll
  for (int j = 0; j < 7; ++j) {
    const int tt = t - 6 + j;
    if (tt >= 0) acc += conv_w[d * 7 + j] * bf2f(up[(j - 6) * 1024]);
  }
  const float g = sigmoidf_(gacc[idx] + gate_b[d]);
  h[idx] = f2bf(acc * g);
}

// ---------------------------------------------------------------------------
// Chunked scans of u (T=2048, 16 chunks of 128), 16 decay rates each.
// ---------------------------------------------------------------------------
__global__ __launch_bounds__(256) void scan1u_kernel(
    const unsigned short* __restrict__ u, const float* __restrict__ decay_logit,
    float* __restrict__ carry) {
  const int gid = blockIdx.x * 256 + threadIdx.x;  // 0..32767
  const int d = gid & 1023;
  const int b = (gid >> 10) & 1;
  const int c = gid >> 11;
  float a[16], s[16];
#pragma unroll
  for (int k = 0; k < 16; ++k) { a[k] = sigmoidf_(decay_logit[k]); s[k] = 0.f; }
  const unsigned short* p = u + ((size_t)b * 2048 + c * 128) * 1024 + d;
#pragma unroll 2
  for (int t = 0; t < 128; ++t) {
    const float uv = bf2f(*p);
    p += 1024;
#pragma unroll
    for (int k = 0; k < 16; ++k) s[k] = fmaf(a[k], s[k], (1.f - a[k]) * uv);
  }
#pragma unroll
  for (int k = 0; k < 16; ++k)
    carry[(size_t)((c * 2 + b) * 16 + k) * 1024 + d] = s[k];
}

__global__ __launch_bounds__(256) void scan2u_kernel(
    float* __restrict__ carry, const float* __restrict__ decay_logit) {
  const int gid = blockIdx.x * 256 + threadIdx.x;  // 0..32767
  const int d = gid & 1023;
  const int k = (gid >> 10) & 15;
  const int b = gid >> 14;
  const float a = sigmoidf_(decay_logit[k]);
  float aL = a;
#pragma unroll
  for (int i = 0; i < 7; ++i) aL *= aL;  // a^128
  float s = 0.f;
#pragma unroll
  for (int c = 0; c < 16; ++c) {
    const size_t idx = (size_t)((c * 2 + b) * 16 + k) * 1024 + d;
    const float Lc = carry[idx];
    carry[idx] = s;
    s = fmaf(aL, s, Lc);
  }
}

__global__ __launch_bounds__(256) void scan3u_kernel(
    const unsigned short* __restrict__ u, const float* __restrict__ decay_logit,
    const float* __restrict__ carry, unsigned short* __restrict__ Ucat) {
  const int gid = blockIdx.x * 256 + threadIdx.x;  // 0..524287
  const int d = gid & 1023;
  const int k = (gid >> 10) & 15;
  const int b = (gid >> 14) & 1;
  const int c = gid >> 15;
  const float a = sigmoidf_(decay_logit[k]);
  const float na = 1.f - a;
  float s = carry[(size_t)((c * 2 + b) * 16 + k) * 1024 + d];
  const unsigned short* p = u + ((size_t)b * 2048 + c * 128) * 1024 + d;
  unsigned short* q = Ucat + ((size_t)b * 2048 + c * 128) * 16384 + k * 1024 + d;
#pragma unroll 4
  for (int t = 0; t < 128; ++t) {
    s = fmaf(a, s, na * bf2f(*p));
    *q = f2bf(s);
    p += 1024;
    q += 16384;
  }
}

// ---------------------------------------------------------------------------
// out = x + LOC + down_b[d]
// ---------------------------------------------------------------------------
__global__ __launch_bounds__(256) void fold_kernel(
    const float* __restrict__ x, const float* __restrict__ loc,
    const float* __restrict__ down_b, float* __restrict__ out) {
  const size_t idx = (size_t)blockIdx.x * 256 + threadIdx.x;
  out[idx] = x[idx] + loc[idx] + down_b[idx & 1023];
}

// ---------------------------------------------------------------------------
extern "C" void kernel_launch(void* const* d_in, const int* in_sizes, int n_in,
                              void* d_out, int out_size, void* d_ws,
                              size_t ws_size, hipStream_t stream) {
  const float* x      = (const float*)d_in[0];
  const float* conv_w = (const float*)d_in[1];
  const float* gate_w = (const float*)d_in[2];
  const float* gate_b = (const float*)d_in[3];
  const float* up_w   = (const float*)d_in[4];
  const float* up_b   = (const float*)d_in[5];
  const float* down_w = (const float*)d_in[6];
  const float* down_b = (const float*)d_in[7];
  const float* sin_w  = (const float*)d_in[8];
  const float* sout_w = (const float*)d_in[9];
  const float* decay  = (const float*)d_in[10];
  const float* gl_w   = (const float*)d_in[11];
  const float* gl_b   = (const float*)d_in[12];
  float* out = (float*)d_out;
  char* ws = (char*)d_ws;

  // Workspace (MB offsets), lifetime-overlapped, peak 170 MB (+16 KB GL):
  //  0..128 : Ucat (written by scan3u). Earlier the region holds:
  //           GWT@0(2) Hb@10(8) UWT@18(4) Mb@22(16) DWT@38(4) (dead at fold),
  //           then SB@0..32, OT@32..64 (dead after gemm_mt).
  //  128..144: GACC f32 (gate logits; dead after sigconv) -> later MT low half
  //  144..160: LOC f32 (dead after fold)                  -> later MT high half
  //  128..160: MT bf16 (written by gemm_mt, after GACC/LOC are dead)
  //  160..168: U bf16 (dead after scan3u)
  //  168..170: CARRY f32
  //  170     : GL (16 KB)
  auto Ucat = (unsigned short*)(ws + ((size_t)0 << 20));
  auto GWT  = (unsigned short*)(ws + ((size_t)0 << 20));
  auto Hb   = (unsigned short*)(ws + ((size_t)10 << 20));
  auto UWT  = (unsigned short*)(ws + ((size_t)18 << 20));
  auto Mb   = (unsigned short*)(ws + ((size_t)22 << 20));
  auto DWT  = (unsigned short*)(ws + ((size_t)38 << 20));
  auto SB   = (unsigned short*)(ws + ((size_t)0 << 20));
  auto OT   = (unsigned short*)(ws + ((size_t)32 << 20));
  auto GACC = (float*)(ws + ((size_t)128 << 20));
  auto LOC  = (float*)(ws + ((size_t)144 << 20));
  auto MT   = (unsigned short*)(ws + ((size_t)128 << 20));
  auto U    = (unsigned short*)(ws + ((size_t)160 << 20));
  auto CARRY= (float*)(ws + ((size_t)168 << 20));
  auto GL   = (float*)(ws + ((size_t)170 << 20));

  rmsnorm_kernel<<<4096, 256, 0, stream>>>(x, gl_w, gl_b, U, GL);

  // ---- local path ----
  hipMemsetAsync(GACC, 0, (size_t)16 << 20, stream);
  transpose_kernel<<<dim3(32, 32), 256, 0, stream>>>(gate_w, GWT, 1024, 1024);
  gemm_atomic<0><<<dim3(32, 8, 2), 256, 0, stream>>>(U, GWT, GACC, 1024, 1024,
                                                     512, nullptr);
  sigconv_kernel<<<16384, 256, 0, stream>>>(U, conv_w, GACC, gate_b, Hb);
  transpose_kernel<<<dim3(64, 32), 256, 0, stream>>>(up_w, UWT, 1024, 2048);
  gemm_bt<2><<<dim3(32, 16), 256, 0, stream>>>(Hb, UWT, up_b, Mb, 2048, 1024);
  hipMemsetAsync(LOC, 0, (size_t)16 << 20, stream);
  transpose_kernel<<<dim3(32, 64), 256, 0, stream>>>(down_w, DWT, 2048, 1024);
  gemm_atomic<0><<<dim3(32, 8, 4), 256, 0, stream>>>(Mb, DWT, LOC, 1024, 2048,
                                                     512, nullptr);
  fold_kernel<<<16384, 256, 0, stream>>>(x, LOC, down_b, out);

  // ---- composite long-path weights: MT = [sout_k^T @ sin_k^T]_k ----
  cast_kernel<<<16384, 256, 0, stream>>>(sin_w, SB);
  transpose_kernel<<<dim3(32, 512), 256, 0, stream>>>(sout_w, OT, 16384, 1024);
  gemm_mt<<<dim3(8, 8, 16), 256, 0, stream>>>(OT, SB, MT);

  // ---- 16 leaky scans of u -> Ucat (B,T,K*D) ----
  scan1u_kernel<<<128, 256, 0, stream>>>(U, decay, CARRY);
  scan2u_kernel<<<128, 256, 0, stream>>>(CARRY, decay);
  scan3u_kernel<<<2048, 256, 0, stream>>>(U, decay, CARRY, Ucat);

  // ---- long path: out += sigmoid(gl) * (Ucat @ MT^T), split-K x6 atomic ----
  gemm_atomic<1><<<dim3(32, 8, 6), 256, 0, stream>>>(Ucat, MT, out, 1024, 16384,
                                                     2752, GL);
}

// Round 6
// 591.170 us; speedup vs baseline: 1.1997x; 1.1997x over previous
//
#include <hip/hip_runtime.h>
#include <cstdint>
#include <cstddef>

typedef __attribute__((ext_vector_type(8))) short short8;
typedef __attribute__((ext_vector_type(4))) float floatx4;

#define DEV static __device__ __forceinline__

// partial-buffer stride: 4096 x 1024 elements
#define PSTRIDE ((size_t)4096 * 1024)

DEV unsigned short f2bf(float f) {
  union { float f; uint32_t u; } v; v.f = f;
  uint32_t r = v.u + 0x7fffu + ((v.u >> 16) & 1u);
  return (unsigned short)(r >> 16);
}
DEV float bf2f(unsigned short h) {
  union { uint32_t u; float f; } v; v.u = ((uint32_t)h) << 16; return v.f;
}
DEV float sigmoidf_(float x) { return 1.f / (1.f + __expf(-x)); }

DEV void gld_lds16(const unsigned short* g, unsigned short* l) {
  __builtin_amdgcn_global_load_lds(
      (const __attribute__((address_space(1))) void*)g,
      (__attribute__((address_space(3))) void*)l, 16, 0, 0);
}

// ---------------------------------------------------------------------------
// fp32 (Kdim x Ndim) row-major -> bf16 (Ndim x Kdim) row-major
// ---------------------------------------------------------------------------
__global__ __launch_bounds__(256) void transpose_kernel(
    const float* __restrict__ W, unsigned short* __restrict__ Wt,
    int Kdim, int Ndim) {
  __shared__ float tile[32][33];
  const int n0 = blockIdx.x * 32;
  const int k0 = blockIdx.y * 32;
  const int tx = threadIdx.x & 31;
  const int ty = threadIdx.x >> 5;
#pragma unroll
  for (int r = 0; r < 32; r += 8)
    tile[ty + r][tx] = W[(size_t)(k0 + ty + r) * Ndim + n0 + tx];
  __syncthreads();
#pragma unroll
  for (int r = 0; r < 32; r += 8)
    Wt[(size_t)(n0 + ty + r) * Kdim + k0 + tx] = f2bf(tile[tx][ty + r]);
}

// flat fp32 -> bf16 cast, 4 elements/thread
__global__ __launch_bounds__(256) void cast_kernel(
    const float* __restrict__ W, unsigned short* __restrict__ Wb) {
  const size_t i = (size_t)blockIdx.x * 256 + threadIdx.x;
  const float4 v = ((const float4*)W)[i];
  ushort4 o;
  o.x = f2bf(v.x); o.y = f2bf(v.y); o.z = f2bf(v.z); o.w = f2bf(v.w);
  ((ushort4*)Wb)[i] = o;
}

// ---------------------------------------------------------------------------
// RMSNorm + u (bf16) + gl logit per row. One block per row.
// ---------------------------------------------------------------------------
__global__ __launch_bounds__(256) void rmsnorm_kernel(
    const float* __restrict__ x, const float* __restrict__ gl_w,
    const float* __restrict__ gl_b, unsigned short* __restrict__ u,
    float* __restrict__ gl_logit) {
  const int row = blockIdx.x;
  const int tid = threadIdx.x;
  const float4 v = ((const float4*)(x + (size_t)row * 1024))[tid];
  float ss = v.x * v.x + v.y * v.y + v.z * v.z + v.w * v.w;
#pragma unroll
  for (int o = 32; o > 0; o >>= 1) ss += __shfl_down(ss, o, 64);
  __shared__ float red[4];
  if ((tid & 63) == 0) red[tid >> 6] = ss;
  __syncthreads();
  const float tot = red[0] + red[1] + red[2] + red[3];
  const float r = rsqrtf(tot * (1.f / 1024.f) + 1e-6f);
  const float ux = v.x * r, uy = v.y * r, uz = v.z * r, uw = v.w * r;
  ushort4 ub;
  ub.x = f2bf(ux); ub.y = f2bf(uy); ub.z = f2bf(uz); ub.w = f2bf(uw);
  ((ushort4*)(u + (size_t)row * 1024))[tid] = ub;
  const float4 w4 = ((const float4*)gl_w)[tid];
  float dot = ux * w4.x + uy * w4.y + uz * w4.z + uw * w4.w;
#pragma unroll
  for (int o = 32; o > 0; o >>= 1) dot += __shfl_down(dot, o, 64);
  __syncthreads();
  if ((tid & 63) == 0) red[tid >> 6] = dot;
  __syncthreads();
  if (tid == 0) gl_logit[row] = red[0] + red[1] + red[2] + red[3] + gl_b[0];
}

// ---------------------------------------------------------------------------
// Direct GEMM: C = A * Bt^T, m97 structure. EPI 2 = bias+silu -> bf16.
// ---------------------------------------------------------------------------
template <int EPI>
__global__ __launch_bounds__(256, 2) void gemm_bt(
    const unsigned short* __restrict__ A, const unsigned short* __restrict__ Bt,
    const float* __restrict__ bias, void* __restrict__ Cout, int Ndim, int Kdim) {
  __shared__ unsigned short As[128 * 32];
  __shared__ unsigned short Bs[128 * 32];
  const int tid = threadIdx.x;
  const int wave = tid >> 6;
  const int lane = tid & 63;
  const size_t row0 = (size_t)blockIdx.x * 128;
  const size_t col0 = (size_t)blockIdx.y * 128;

  const int srow = wave * 32 + (lane >> 2);
  const int kofs = (lane & 3) * 8;
  const unsigned short* pA0 = A + (row0 + srow) * (size_t)Kdim + kofs;
  const unsigned short* pA1 = A + (row0 + srow + 16) * (size_t)Kdim + kofs;
  const unsigned short* pB0 = Bt + (col0 + srow) * (size_t)Kdim + kofs;
  const unsigned short* pB1 = Bt + (col0 + srow + 16) * (size_t)Kdim + kofs;
  unsigned short* lA0 = &As[(wave * 2 + 0) * 512];
  unsigned short* lA1 = &As[(wave * 2 + 1) * 512];
  unsigned short* lB0 = &Bs[(wave * 2 + 0) * 512];
  unsigned short* lB1 = &Bs[(wave * 2 + 1) * 512];

  const int wm = (wave & 1) * 64;
  const int wn = (wave >> 1) * 64;
  const int lr = lane & 15;
  const int lq = lane >> 4;
  const int a_off = (wm + lr) * 32 + lq * 8;
  const int b_off = (wn + lr) * 32 + lq * 8;

  floatx4 acc[4][4];
#pragma unroll
  for (int i = 0; i < 4; i++)
#pragma unroll
    for (int j = 0; j < 4; j++) acc[i][j] = floatx4{0.f, 0.f, 0.f, 0.f};

  for (int kt = 0; kt < Kdim; kt += 32) {
    __syncthreads();
    gld_lds16(pA0, lA0);
    gld_lds16(pA1, lA1);
    gld_lds16(pB0, lB0);
    gld_lds16(pB1, lB1);
    pA0 += 32; pA1 += 32; pB0 += 32; pB1 += 32;
    __syncthreads();
    short8 af[4], bfr[4];
#pragma unroll
    for (int i = 0; i < 4; i++) af[i] = *(const short8*)&As[a_off + i * 16 * 32];
#pragma unroll
    for (int j = 0; j < 4; j++) bfr[j] = *(const short8*)&Bs[b_off + j * 16 * 32];
#pragma unroll
    for (int i = 0; i < 4; i++)
#pragma unroll
      for (int j = 0; j < 4; j++)
        acc[i][j] = __builtin_amdgcn_mfma_f32_16x16x32_bf16(af[i], bfr[j], acc[i][j], 0, 0, 0);
  }

#pragma unroll
  for (int i = 0; i < 4; i++) {
    const size_t rbase = row0 + wm + 16 * i + lq * 4;
#pragma unroll
    for (int j = 0; j < 4; j++) {
      const size_t c = col0 + wn + 16 * j + lr;
#pragma unroll
      for (int r = 0; r < 4; r++) {
        float v = acc[i][j][r];
        const size_t off = (rbase + r) * (size_t)Ndim + c;
        if constexpr (EPI == 2) {
          v += bias[c];
          ((unsigned short*)Cout)[off] = f2bf(v * sigmoidf_(v));
        } else {
          ((unsigned short*)Cout)[off] = f2bf(v);
        }
      }
    }
  }
}

// ---------------------------------------------------------------------------
// Generic split-K GEMM -> bf16 partials at PBase + split*PSTRIDE. N = 1024.
// ---------------------------------------------------------------------------
__global__ __launch_bounds__(256, 2) void gemm_splitkP(
    const unsigned short* __restrict__ A, const unsigned short* __restrict__ Bt,
    unsigned short* __restrict__ PBase, int Kdim, int splitLen) {
  __shared__ unsigned short As[128 * 32];
  __shared__ unsigned short Bs[128 * 32];
  const int split = blockIdx.z;
  const int k0 = split * splitLen;
  const int klen = min(splitLen, Kdim - k0);
  const int tid = threadIdx.x;
  const int wave = tid >> 6;
  const int lane = tid & 63;
  const size_t row0 = (size_t)blockIdx.x * 128;
  const size_t col0 = (size_t)blockIdx.y * 128;

  const int srow = wave * 32 + (lane >> 2);
  const int kofs = (lane & 3) * 8;
  const unsigned short* pA0 = A + (row0 + srow) * (size_t)Kdim + k0 + kofs;
  const unsigned short* pA1 = A + (row0 + srow + 16) * (size_t)Kdim + k0 + kofs;
  const unsigned short* pB0 = Bt + (col0 + srow) * (size_t)Kdim + k0 + kofs;
  const unsigned short* pB1 = Bt + (col0 + srow + 16) * (size_t)Kdim + k0 + kofs;
  unsigned short* lA0 = &As[(wave * 2 + 0) * 512];
  unsigned short* lA1 = &As[(wave * 2 + 1) * 512];
  unsigned short* lB0 = &Bs[(wave * 2 + 0) * 512];
  unsigned short* lB1 = &Bs[(wave * 2 + 1) * 512];

  const int wm = (wave & 1) * 64;
  const int wn = (wave >> 1) * 64;
  const int lr = lane & 15;
  const int lq = lane >> 4;
  const int a_off = (wm + lr) * 32 + lq * 8;
  const int b_off = (wn + lr) * 32 + lq * 8;

  floatx4 acc[4][4];
#pragma unroll
  for (int i = 0; i < 4; i++)
#pragma unroll
    for (int j = 0; j < 4; j++) acc[i][j] = floatx4{0.f, 0.f, 0.f, 0.f};

  for (int kt = 0; kt < klen; kt += 32) {
    __syncthreads();
    gld_lds16(pA0, lA0);
    gld_lds16(pA1, lA1);
    gld_lds16(pB0, lB0);
    gld_lds16(pB1, lB1);
    pA0 += 32; pA1 += 32; pB0 += 32; pB1 += 32;
    __syncthreads();
    short8 af[4], bfr[4];
#pragma unroll
    for (int i = 0; i < 4; i++) af[i] = *(const short8*)&As[a_off + i * 16 * 32];
#pragma unroll
    for (int j = 0; j < 4; j++) bfr[j] = *(const short8*)&Bs[b_off + j * 16 * 32];
#pragma unroll
    for (int i = 0; i < 4; i++)
#pragma unroll
      for (int j = 0; j < 4; j++)
        acc[i][j] = __builtin_amdgcn_mfma_f32_16x16x32_bf16(af[i], bfr[j], acc[i][j], 0, 0, 0);
  }

  unsigned short* P = PBase + (size_t)split * PSTRIDE;
#pragma unroll
  for (int i = 0; i < 4; i++) {
    const size_t rbase = row0 + wm + 16 * i + lq * 4;
#pragma unroll
    for (int j = 0; j < 4; j++) {
      const size_t c = col0 + wn + 16 * j + lr;
#pragma unroll
      for (int r = 0; r < 4; r++)
        P[(rbase + r) * 1024 + c] = f2bf(acc[i][j][r]);
    }
  }
}

// ---------------------------------------------------------------------------
// Batched strided GEMM for composite weights:
//   MT[d_out][kb*1024+d_in] = sum_dmid OT[d_out][kb*1024+dmid]*SB[d_in][kb*1024+dmid]
// ---------------------------------------------------------------------------
__global__ __launch_bounds__(256, 2) void gemm_mt(
    const unsigned short* __restrict__ OT, const unsigned short* __restrict__ SB,
    unsigned short* __restrict__ MT) {
  __shared__ unsigned short As[128 * 32];
  __shared__ unsigned short Bs[128 * 32];
  const int kb = blockIdx.z;
  const int tid = threadIdx.x;
  const int wave = tid >> 6;
  const int lane = tid & 63;
  const size_t row0 = (size_t)blockIdx.x * 128;
  const size_t col0 = (size_t)blockIdx.y * 128;
  const size_t ld = 16384;

  const int srow = wave * 32 + (lane >> 2);
  const int kofs = (lane & 3) * 8;
  const unsigned short* pA0 = OT + (row0 + srow) * ld + kb * 1024 + kofs;
  const unsigned short* pA1 = OT + (row0 + srow + 16) * ld + kb * 1024 + kofs;
  const unsigned short* pB0 = SB + (col0 + srow) * ld + kb * 1024 + kofs;
  const unsigned short* pB1 = SB + (col0 + srow + 16) * ld + kb * 1024 + kofs;
  unsigned short* lA0 = &As[(wave * 2 + 0) * 512];
  unsigned short* lA1 = &As[(wave * 2 + 1) * 512];
  unsigned short* lB0 = &Bs[(wave * 2 + 0) * 512];
  unsigned short* lB1 = &Bs[(wave * 2 + 1) * 512];

  const int wm = (wave & 1) * 64;
  const int wn = (wave >> 1) * 64;
  const int lr = lane & 15;
  const int lq = lane >> 4;
  const int a_off = (wm + lr) * 32 + lq * 8;
  const int b_off = (wn + lr) * 32 + lq * 8;

  floatx4 acc[4][4];
#pragma unroll
  for (int i = 0; i < 4; i++)
#pragma unroll
    for (int j = 0; j < 4; j++) acc[i][j] = floatx4{0.f, 0.f, 0.f, 0.f};

  for (int kt = 0; kt < 1024; kt += 32) {
    __syncthreads();
    gld_lds16(pA0, lA0);
    gld_lds16(pA1, lA1);
    gld_lds16(pB0, lB0);
    gld_lds16(pB1, lB1);
    pA0 += 32; pA1 += 32; pB0 += 32; pB1 += 32;
    __syncthreads();
    short8 af[4], bfr[4];
#pragma unroll
    for (int i = 0; i < 4; i++) af[i] = *(const short8*)&As[a_off + i * 16 * 32];
#pragma unroll
    for (int j = 0; j < 4; j++) bfr[j] = *(const short8*)&Bs[b_off + j * 16 * 32];
#pragma unroll
    for (int i = 0; i < 4; i++)
#pragma unroll
      for (int j = 0; j < 4; j++)
        acc[i][j] = __builtin_amdgcn_mfma_f32_16x16x32_bf16(af[i], bfr[j], acc[i][j], 0, 0, 0);
  }

#pragma unroll
  for (int i = 0; i < 4; i++) {
    const size_t rbase = row0 + wm + 16 * i + lq * 4;
#pragma unroll
    for (int j = 0; j < 4; j++) {
      const size_t c = col0 + wn + 16 * j + lr;
#pragma unroll
      for (int r = 0; r < 4; r++)
        MT[(rbase + r) * ld + kb * 1024 + c] = f2bf(acc[i][j][r]);
    }
  }
}

// ---------------------------------------------------------------------------
// h = conv7(u) * sigmoid(GP0 + GP1 + gate_b)   (gate split-K partials, bf16)
// ---------------------------------------------------------------------------
__global__ __launch_bounds__(256) void convgate2_kernel(
    const unsigned short* __restrict__ u, const float* __restrict__ conv_w,
    const unsigned short* __restrict__ gp, const float* __restrict__ gate_b,
    unsigned short* __restrict__ h) {
  const size_t idx = (size_t)blockIdx.x * 256 + threadIdx.x;
  const int d = (int)(idx & 1023);
  const int t = (int)((idx >> 10) & 2047);
  const unsigned short* up = u + idx;
  float acc = 0.f;
#pragma unroll
  for (int j = 0; j < 7; ++j) {
    const int tt = t - 6 + j;
    if (tt >= 0) acc += conv_w[d * 7 + j] * bf2f(up[(j - 6) * 1024]);
  }
  const float logit = bf2f(gp[idx]) + bf2f(gp[idx + PSTRIDE]) + gate_b[d];
  h[idx] = f2bf(acc * sigmoidf_(logit));
}

// ---------------------------------------------------------------------------
// out = x + (DP0+DP1+DP2+DP3) + down_b    (down split-K partials, bf16)
// ---------------------------------------------------------------------------
__global__ __launch_bounds__(256) void fold4_kernel(
    const float* __restrict__ x, const unsigned short* __restrict__ dp,
    const float* __restrict__ down_b, float* __restrict__ out) {
  const size_t idx = (size_t)blockIdx.x * 256 + threadIdx.x;
  const float s = bf2f(dp[idx]) + bf2f(dp[idx + PSTRIDE]) +
                  bf2f(dp[idx + 2 * PSTRIDE]) + bf2f(dp[idx + 3 * PSTRIDE]);
  out[idx] = x[idx] + s + down_b[idx & 1023];
}

// ---------------------------------------------------------------------------
// out += sigmoid(gl[row]) * (P0+P1+P2)   (sout split-K partials, bf16)
// ---------------------------------------------------------------------------
__global__ __launch_bounds__(256) void reduce3_kernel(
    const unsigned short* __restrict__ p, const float* __restrict__ gl,
    float* __restrict__ out) {
  const size_t idx = (size_t)blockIdx.x * 256 + threadIdx.x;
  const float g = sigmoidf_(gl[idx >> 10]);
  const float s = bf2f(p[idx]) + bf2f(p[idx + PSTRIDE]) + bf2f(p[idx + 2 * PSTRIDE]);
  out[idx] += g * s;
}

// ---------------------------------------------------------------------------
// Chunked scans of u (T=2048, 16 chunks of 128), 16 decay rates each.
// ---------------------------------------------------------------------------
__global__ __launch_bounds__(256) void scan1u_kernel(
    const unsigned short* __restrict__ u, const float* __restrict__ decay_logit,
    float* __restrict__ carry) {
  const int gid = blockIdx.x * 256 + threadIdx.x;  // 0..32767
  const int d = gid & 1023;
  const int b = (gid >> 10) & 1;
  const int c = gid >> 11;
  float a[16], s[16];
#pragma unroll
  for (int k = 0; k < 16; ++k) { a[k] = sigmoidf_(decay_logit[k]); s[k] = 0.f; }
  const unsigned short* p = u + ((size_t)b * 2048 + c * 128) * 1024 + d;
#pragma unroll 2
  for (int t = 0; t < 128; ++t) {
    const float uv = bf2f(*p);
    p += 1024;
#pragma unroll
    for (int k = 0; k < 16; ++k) s[k] = fmaf(a[k], s[k], (1.f - a[k]) * uv);
  }
#pragma unroll
  for (int k = 0; k < 16; ++k)
    carry[(size_t)((c * 2 + b) * 16 + k) * 1024 + d] = s[k];
}

__global__ __launch_bounds__(256) void scan2u_kernel(
    float* __restrict__ carry, const float* __restrict__ decay_logit) {
  const int gid = blockIdx.x * 256 + threadIdx.x;  // 0..32767
  const int d = gid & 1023;
  const int k = (gid >> 10) & 15;
  const int b = gid >> 14;
  const float a = sigmoidf_(decay_logit[k]);
  float aL = a;
#pragma unroll
  for (int i = 0; i < 7; ++i) aL *= aL;  // a^128
  float s = 0.f;
#pragma unroll
  for (int c = 0; c < 16; ++c) {
    const size_t idx = (size_t)((c * 2 + b) * 16 + k) * 1024 + d;
    const float Lc = carry[idx];
    carry[idx] = s;
    s = fmaf(aL, s, Lc);
  }
}

__global__ __launch_bounds__(256) void scan3u_kernel(
    const unsigned short* __restrict__ u, const float* __restrict__ decay_logit,
    const float* __restrict__ carry, unsigned short* __restrict__ Ucat) {
  const int gid = blockIdx.x * 256 + threadIdx.x;  // 0..524287
  const int d = gid & 1023;
  const int k = (gid >> 10) & 15;
  const int b = (gid >> 14) & 1;
  const int c = gid >> 15;
  const float a = sigmoidf_(decay_logit[k]);
  const float na = 1.f - a;
  float s = carry[(size_t)((c * 2 + b) * 16 + k) * 1024 + d];
  const unsigned short* p = u + ((size_t)b * 2048 + c * 128) * 1024 + d;
  unsigned short* q = Ucat + ((size_t)b * 2048 + c * 128) * 16384 + k * 1024 + d;
#pragma unroll 4
  for (int t = 0; t < 128; ++t) {
    s = fmaf(a, s, na * bf2f(*p));
    *q = f2bf(s);
    p += 1024;
    q += 16384;
  }
}

// ---------------------------------------------------------------------------
extern "C" void kernel_launch(void* const* d_in, const int* in_sizes, int n_in,
                              void* d_out, int out_size, void* d_ws,
                              size_t ws_size, hipStream_t stream) {
  const float* x      = (const float*)d_in[0];
  const float* conv_w = (const float*)d_in[1];
  const float* gate_w = (const float*)d_in[2];
  const float* gate_b = (const float*)d_in[3];
  const float* up_w   = (const float*)d_in[4];
  const float* up_b   = (const float*)d_in[5];
  const float* down_w = (const float*)d_in[6];
  const float* down_b = (const float*)d_in[7];
  const float* sin_w  = (const float*)d_in[8];
  const float* sout_w = (const float*)d_in[9];
  const float* decay  = (const float*)d_in[10];
  const float* gl_w   = (const float*)d_in[11];
  const float* gl_b   = (const float*)d_in[12];
  float* out = (float*)d_out;
  char* ws = (char*)d_ws;

  // Workspace (MB offsets), lifetime-overlapped, peak 184 MB + 16 KB (proven):
  //  phase 1 (local path):   GWT@0(2) GP@2(16,2 partials) Hb@18(8) UWT@26(4)
  //                          Mb@30(16) DWT@46(4) DP@50(32,4 partials)
  //  phase 2 (weights):      SB@0(32) OT@32(32)  [after fold]  MT@128(32)
  //  phase 3 (scan+GEMM):    Ucat@0(128)  P@160(24,3 partials)
  //  persistent:             U@160(8, dead after scan3u) CARRY@168(2, dead
  //                          after scan3u) GL@184(16 KB)
  auto Ucat = (unsigned short*)(ws + ((size_t)0 << 20));
  auto GWT  = (unsigned short*)(ws + ((size_t)0 << 20));
  auto GP   = (unsigned short*)(ws + ((size_t)2 << 20));
  auto Hb   = (unsigned short*)(ws + ((size_t)18 << 20));
  auto UWT  = (unsigned short*)(ws + ((size_t)26 << 20));
  auto Mb   = (unsigned short*)(ws + ((size_t)30 << 20));
  auto DWT  = (unsigned short*)(ws + ((size_t)46 << 20));
  auto DP   = (unsigned short*)(ws + ((size_t)50 << 20));
  auto SB   = (unsigned short*)(ws + ((size_t)0 << 20));
  auto OT   = (unsigned short*)(ws + ((size_t)32 << 20));
  auto MT   = (unsigned short*)(ws + ((size_t)128 << 20));
  auto U    = (unsigned short*)(ws + ((size_t)160 << 20));
  auto P    = (unsigned short*)(ws + ((size_t)160 << 20));
  auto CARRY= (float*)(ws + ((size_t)168 << 20));
  auto GL   = (float*)(ws + ((size_t)184 << 20));

  rmsnorm_kernel<<<4096, 256, 0, stream>>>(x, gl_w, gl_b, U, GL);

  // ---- local path (split-K everywhere, bf16 partials, fused reduces) ----
  transpose_kernel<<<dim3(32, 32), 256, 0, stream>>>(gate_w, GWT, 1024, 1024);
  gemm_splitkP<<<dim3(32, 8, 2), 256, 0, stream>>>(U, GWT, GP, 1024, 512);
  convgate2_kernel<<<16384, 256, 0, stream>>>(U, conv_w, GP, gate_b, Hb);
  transpose_kernel<<<dim3(64, 32), 256, 0, stream>>>(up_w, UWT, 1024, 2048);
  gemm_bt<2><<<dim3(32, 16), 256, 0, stream>>>(Hb, UWT, up_b, Mb, 2048, 1024);
  transpose_kernel<<<dim3(32, 64), 256, 0, stream>>>(down_w, DWT, 2048, 1024);
  gemm_splitkP<<<dim3(32, 8, 4), 256, 0, stream>>>(Mb, DWT, DP, 2048, 512);
  fold4_kernel<<<16384, 256, 0, stream>>>(x, DP, down_b, out);

  // ---- composite long-path weights: MT = [sout_k^T @ sin_k^T]_k ----
  cast_kernel<<<16384, 256, 0, stream>>>(sin_w, SB);
  transpose_kernel<<<dim3(32, 512), 256, 0, stream>>>(sout_w, OT, 16384, 1024);
  gemm_mt<<<dim3(8, 8, 16), 256, 0, stream>>>(OT, SB, MT);

  // ---- 16 leaky scans of u -> Ucat (B,T,K*D) ----
  scan1u_kernel<<<128, 256, 0, stream>>>(U, decay, CARRY);
  scan2u_kernel<<<128, 256, 0, stream>>>(CARRY, decay);
  scan3u_kernel<<<2048, 256, 0, stream>>>(U, decay, CARRY, Ucat);

  // ---- long path: split-K x3, bf16 partials, gated reduce ----
  gemm_splitkP<<<dim3(32, 8, 3), 256, 0, stream>>>(Ucat, MT, P, 16384, 5472);
  reduce3_kernel<<<16384, 256, 0, stream>>>(P, GL, out);
}